// Round 2
// baseline (35553.024 us; speedup 1.0000x reference)
//
#include <hip/hip_runtime.h>
#include <math.h>

// Problem constants
#define B 128
#define T 1024
#define E 256
#define H 512

// ws layout (floats):
//   h_buf : 2 * [512][128]  (double-buffered, [unit][batch])
//   last_h: [512][128]
//   last_c: [512][128]
//   flags : 8 groups x 64 ints (one 128B slot-line per group; slots 0..31 used)
#define HBUF_OFF   0
#define LASTH_OFF  (2*65536)
#define LASTC_OFF  (3*65536)
#define FLAG_OFF   (4*65536)

// Accurate transcendentals (OCML expf/tanhf): matched np bit-exact previously.
__device__ __forceinline__ float sigm_f(float x) {
    return 1.f / (1.f + expf(-x));
}
__device__ __forceinline__ float tanh_f(float x) {
    return tanhf(x);
}
__device__ __forceinline__ void fma4(float4& a, const float4 w, const float4 x) {
    a.x = fmaf(w.x, x.x, a.x);
    a.y = fmaf(w.y, x.y, a.y);
    a.z = fmaf(w.z, x.z, a.z);
    a.w = fmaf(w.w, x.w, a.w);
}

// ---------------------------------------------------------------------------
// Persistent LSTM: whole T=1024 loop in one cooperative kernel.
// 256 blocks x 1024 threads. LDS padded >80KB => exactly 1 block/CU (256 CUs).
// g = bid>>5 (8 batch groups of 16 rows), m = bid&31 (32 unit groups of 16).
// Cross-block dependency is ONLY h(t) within a batch group (32 blocks):
//   - h exchanged via agent-scope relaxed atomics (LLC-coherent; no L2 inv or
//     writeback anywhere => weights stay L2-resident across all steps).
//   - per-group barrier: per-block FLAG SLOT (store t+1, relaxed) + all-wave
//     poll of the 32-slot line. No RMW atomics, no release/wbl2, no leader.
//     The vmcnt-draining __syncthreads() before the flag store guarantees the
//     h stores are at the LLC before the flag becomes visible.
//   - 2 h buffers + 1 barrier/step is race-free: writers of h(t+2) start only
//     after all flags>=t+1, i.e. after every peer finished READING h(t).
// c tile is block-owned => lives in LDS for the whole kernel.
__global__ __launch_bounds__(1024) void lstm_persistent(
    const int* __restrict__ tokens, const float* __restrict__ emb,
    const float* __restrict__ W_ih, const float* __restrict__ b_ih,
    const float* __restrict__ W_hh, const float* __restrict__ b_hh,
    const float* __restrict__ h0, const float* __restrict__ c0,
    float* __restrict__ ws) {
    const int tid = threadIdx.x, bid = blockIdx.x;
    const int g = bid >> 5, m = bid & 31;

    float* h_buf  = ws + HBUF_OFF;
    float* last_h = ws + LASTH_OFF;
    float* last_c = ws + LASTC_OFF;
    int*   flags  = (int*)(ws + FLAG_OFF) + g * 64;   // 32 slots in one line

    __shared__ __align__(16) float  xh[16 * 772];   // [b][k], row-padded 768->772
    __shared__ float4 part[4 * 256];                // [kq][ul*16+b]
    __shared__ int    s_L[16];                      // per-batch Lsteps
    __shared__ float  s_c[256];                     // c[ul*16+b], block-owned
    __shared__ float  lds_pad[4096];                // 16KB: push LDS>80KB => 1 block/CU

    lds_pad[tid & 4095] = 0.f;   // keep the pad live (occupancy limiter)

    // ---- per-batch lengths (all 32 blocks of a group compute identical s_L/Tg)
    if (tid < 16) s_L[tid] = T;
    __syncthreads();
    {
        const int b = tid >> 6;
        const int* tb = tokens + (size_t)(g * 16 + b) * T;
        int fz = T;
        for (int p = (tid & 63); p < T; p += 64)
            if (tb[p] == 0) fz = min(fz, p);
        atomicMin(&s_L[b], fz);
    }
    __syncthreads();
    if (tid < 16) {
        const int f = s_L[tid];
        s_L[tid] = (f == 0 || f == T) ? T : f;
    }
    __syncthreads();
    int Tg = 0;
#pragma unroll
    for (int i = 0; i < 16; ++i) Tg = max(Tg, s_L[i]);

    // ---- init block-owned c tile (same thread reads it later; no sync needed)
    if (tid < 256) {
        const int uli = tid >> 4, bi = tid & 15;
        s_c[tid] = c0[(size_t)(g * 16 + bi) * H + (m * 16 + uli)];
    }

    // ---- stage x(0) (xh x-region is free pre-loop)
    {
        const int b = tid >> 6, kq4 = tid & 63;
        const int tok = tokens[(size_t)(g * 16 + b) * T + 0];
        ((float4*)&xh[b * 772])[kq4] =
            ((const float4*)emb)[(size_t)tok * 64 + kq4];
    }

    // ---- compute-role constants
    const int kq = tid >> 8, ul = (tid >> 4) & 15, cb = tid & 15;
    const int unit = m * 16 + ul;
    const float4* Wi = (const float4*)W_ih;
    const float4* Wh = (const float4*)W_hh;
    const float4* wr0 = Wi + (size_t)(unit) * 64;
    const float4* wr1 = Wi + (size_t)(H + unit) * 64;
    const float4* wr2 = Wi + (size_t)(2 * H + unit) * 64;
    const float4* wr3 = Wi + (size_t)(3 * H + unit) * 64;
    const float4* vr0 = Wh + (size_t)(unit) * 128;
    const float4* vr1 = Wh + (size_t)(H + unit) * 128;
    const float4* vr2 = Wh + (size_t)(2 * H + unit) * 128;
    const float4* vr3 = Wh + (size_t)(3 * H + unit) * 128;
    const int k4lo = kq * 48, k4hi = k4lo + 48;
    const int xlo = min(k4lo, 64), xhi = min(k4hi, 64);
    const int hlo = max(k4lo, 64) - 64, hhi = max(k4hi, 64) - 64;
    const float4* xb = (const float4*)&xh[cb * 772];

    // ---- epilogue constants (used for tid<256; reads in-bounds for all)
    const int ul2 = tid >> 4, b2 = tid & 15;
    const int unit2 = m * 16 + (ul2 & 15);
    const int bg = g * 16 + b2;
    const float bi_i = b_ih[unit2],         bh_i = b_hh[unit2];
    const float bi_f = b_ih[H + unit2],     bh_f = b_hh[H + unit2];
    const float bi_g = b_ih[2 * H + unit2], bh_g = b_hh[2 * H + unit2];
    const float bi_o = b_ih[3 * H + unit2], bh_o = b_hh[3 * H + unit2];

    for (int t = 0; t < Tg; ++t) {
        // ---- stage h(t): xh[b][256+u]
        if (t == 0) {
            const int b = tid >> 6, l = tid & 63;
            const float4* h04 = (const float4*)(h0 + (size_t)(g * 16 + b) * H);
            float4* dst = (float4*)&xh[b * 772 + 256];
            dst[l]      = h04[l];
            dst[64 + l] = h04[64 + l];
        } else {
            // coherent 8B loads from LLC (bypass L1/L2; no cache maintenance)
            const unsigned long long* hs8 = (const unsigned long long*)
                (h_buf + (size_t)(t & 1) * (H * B));
            float2 hv[4];
#pragma unroll
            for (int j = 0; j < 4; ++j) {
                const int idx = j * 1024 + tid;        // [0,4096)
                const int u = idx >> 3, bp = idx & 7;
                unsigned long long v = __hip_atomic_load(
                    &hs8[(size_t)u * 64 + g * 8 + bp],
                    __ATOMIC_RELAXED, __HIP_MEMORY_SCOPE_AGENT);
                hv[j] = __builtin_bit_cast(float2, v);
            }
#pragma unroll
            for (int j = 0; j < 4; ++j) {
                const int idx = j * 1024 + tid;
                const int u = idx >> 3, bp = idx & 7;
                xh[(2 * bp) * 772 + 256 + u]     = hv[j].x;
                xh[(2 * bp + 1) * 772 + 256 + u] = hv[j].y;
            }
        }
        __syncthreads();

        // ---- K-split partial dots (identical arithmetic to verified kernel)
        float4 s0 = {0, 0, 0, 0}, s1 = {0, 0, 0, 0};
        float4 s2 = {0, 0, 0, 0}, s3 = {0, 0, 0, 0};
#pragma unroll 4
        for (int k4 = xlo; k4 < xhi; ++k4) {
            const float4 x = xb[k4];
            fma4(s0, wr0[k4], x);
            fma4(s1, wr1[k4], x);
            fma4(s2, wr2[k4], x);
            fma4(s3, wr3[k4], x);
        }
#pragma unroll 4
        for (int k4 = hlo; k4 < hhi; ++k4) {
            const float4 x = xb[64 + k4];
            fma4(s0, vr0[k4], x);
            fma4(s1, vr1[k4], x);
            fma4(s2, vr2[k4], x);
            fma4(s3, vr3[k4], x);
        }
        float4 p;
        p.x = s0.x + s0.y + s0.z + s0.w;
        p.y = s1.x + s1.y + s1.z + s1.w;
        p.z = s2.x + s2.y + s2.z + s2.w;
        p.w = s3.x + s3.y + s3.z + s3.w;
        part[kq * 256 + (ul * 16 + cb)] = p;
        __syncthreads();

        // ---- stage x(t+1) now (xh x-region free; overlaps the barrier wait)
        if (t + 1 < Tg) {
            const int b = tid >> 6, kq4 = tid & 63;
            const int tok = tokens[(size_t)(g * 16 + b) * T + (t + 1)];
            ((float4*)&xh[b * 772])[kq4] =
                ((const float4*)emb)[(size_t)tok * 64 + kq4];
        }

        // ---- finish gates + elementwise (tid<256)
        if (tid < 256) {
            const float4 q0 = part[tid],       q1 = part[256 + tid];
            const float4 q2 = part[512 + tid], q3 = part[768 + tid];
            const float ai = (q0.x + q1.x) + (q2.x + q3.x) + bi_i + bh_i;
            const float af = (q0.y + q1.y) + (q2.y + q3.y) + bi_f + bh_f;
            const float ag = (q0.z + q1.z) + (q2.z + q3.z) + bi_g + bh_g;
            const float ao = (q0.w + q1.w) + (q2.w + q3.w) + bi_o + bh_o;

            const float ig = sigm_f(ai);
            const float fg = sigm_f(af);
            const float gv = tanh_f(ag);
            const float og = sigm_f(ao);

            const float c_old = s_c[tid];
            const float c_new = fg * c_old + ig * gv;
            const float h_new = og * tanh_f(c_new);
            s_c[tid] = c_new;

            const int idx = unit2 * B + bg;
            __hip_atomic_store(&h_buf[(size_t)((t + 1) & 1) * (H * B) + idx],
                               h_new, __ATOMIC_RELAXED,
                               __HIP_MEMORY_SCOPE_AGENT);
            if (t == s_L[b2] - 1) {
                last_h[idx] = h_new;
                last_c[idx] = c_new;
            }
        }

        // ---- per-group flag barrier (skip after last step: h(Tg) never read)
        if (t < Tg - 1) {
            __syncthreads();   // drains vmcnt: this block's h stores are @ LLC
            if (tid == 0)
                __hip_atomic_store(&flags[m], t + 1, __ATOMIC_RELAXED,
                                   __HIP_MEMORY_SCOPE_AGENT);
            asm volatile("" ::: "memory");
            const int* slot = &flags[tid & 31];
            const int target = t + 1;
            while (true) {
                const int v = __hip_atomic_load(slot, __ATOMIC_RELAXED,
                                                __HIP_MEMORY_SCOPE_AGENT);
                if (__all(v >= target)) break;
                __builtin_amdgcn_s_sleep(1);
            }
            asm volatile("" ::: "memory");
            // no __syncthreads needed: each wave proceeds independently; the
            // loop-top __syncthreads re-converges before xh is read.
        }
    }
}

// ---------------------------------------------------------------------------
// final: y = [h;c] @ W_proj^T + b_proj ; out = y @ W_out^T + b_out
// grid 128 x 256 (unchanged)
__global__ __launch_bounds__(256) void final_kernel(
    const float* __restrict__ ws_ro, const float* __restrict__ W_proj,
    const float* __restrict__ b_proj, const float* __restrict__ W_out,
    const float* __restrict__ b_out, float* __restrict__ out) {
    const int bg = blockIdx.x, tid = threadIdx.x;
    const float* last_h = ws_ro + LASTH_OFF;
    const float* last_c = ws_ro + LASTC_OFF;

    __shared__ __align__(16) float s_hc[2 * H];
    __shared__ float s_y[H];
    for (int u = tid; u < H; u += 256) {
        s_hc[u]     = last_h[u * B + bg];
        s_hc[H + u] = last_c[u * B + bg];
    }
    __syncthreads();

    const float4* hc4 = (const float4*)s_hc;
    const float4* Wp4 = (const float4*)W_proj;
#pragma unroll
    for (int jj = 0; jj < 2; ++jj) {
        const int j = tid + jj * 256;
        const float4* wr = Wp4 + (size_t)j * 256;
        float4 acc = {0, 0, 0, 0};
#pragma unroll 4
        for (int kq = 0; kq < 256; ++kq) fma4(acc, wr[kq], hc4[kq]);
        s_y[j] = acc.x + acc.y + acc.z + acc.w + b_proj[j];
    }
    __syncthreads();

    if (tid < 64) {
        float p0 = 0.f, p1 = 0.f;
        for (int j = tid; j < H; j += 64) {
            const float y = s_y[j];
            p0 = fmaf(y, W_out[j], p0);
            p1 = fmaf(y, W_out[H + j], p1);
        }
#pragma unroll
        for (int off = 32; off; off >>= 1) {
            p0 += __shfl_down(p0, off);
            p1 += __shfl_down(p1, off);
        }
        if (tid == 0) {
            out[bg * 2 + 0] = p0 + b_out[0];
            out[bg * 2 + 1] = p1 + b_out[1];
        }
    }
}

// ---------------------------------------------------------------------------
extern "C" void kernel_launch(void* const* d_in, const int* in_sizes, int n_in,
                              void* d_out, int out_size, void* d_ws, size_t ws_size,
                              hipStream_t stream) {
    const int*   tokens = (const int*)d_in[0];
    const float* emb    = (const float*)d_in[1];
    const float* W_ih   = (const float*)d_in[2];
    const float* b_ih   = (const float*)d_in[3];
    const float* W_hh   = (const float*)d_in[4];
    const float* b_hh   = (const float*)d_in[5];
    const float* W_proj = (const float*)d_in[6];
    const float* b_proj = (const float*)d_in[7];
    const float* W_out  = (const float*)d_in[8];
    const float* b_out  = (const float*)d_in[9];
    const float* h0     = (const float*)d_in[10];
    const float* c0     = (const float*)d_in[11];
    float* out = (float*)d_out;
    float* ws  = (float*)d_ws;

    // zero the per-group flag slots (required every launch/replay)
    hipMemsetAsync((char*)d_ws + (size_t)FLAG_OFF * sizeof(float), 0,
                   8 * 64 * sizeof(int), stream);

    void* kargs[] = {(void*)&tokens, (void*)&emb, (void*)&W_ih, (void*)&b_ih,
                     (void*)&W_hh, (void*)&b_hh, (void*)&h0, (void*)&c0,
                     (void*)&ws};
    // cooperative launch: guarantees all 256 blocks co-resident (1/CU with the
    // LDS pad), which the per-group flag barrier requires.
    hipLaunchCooperativeKernel((const void*)lstm_persistent, dim3(256),
                               dim3(1024), kargs, 0, stream);

    hipLaunchKernelGGL(final_kernel, dim3(B), dim3(256), 0, stream,
                       ws, W_proj, b_proj, W_out, b_out, out);
}

// Round 3
// 32003.638 us; speedup vs baseline: 1.1109x; 1.1109x over previous
//
#include <hip/hip_runtime.h>
#include <math.h>

// Problem constants
#define B 128
#define T 1024
#define E 256
#define H 512

// ws layout (floats):
//   h_buf : 2 * [512][128]  (double-buffered, [unit][batch])
//   last_h: [512][128]
//   last_c: [512][128]
//   flags : 8 groups x 64 ints (one 128B slot-line per group; slots 0..31 used)
#define HBUF_OFF   0
#define LASTH_OFF  (2*65536)
#define LASTC_OFF  (3*65536)
#define FLAG_OFF   (4*65536)

// Accurate transcendentals (OCML expf/tanhf): matched np bit-exact previously.
__device__ __forceinline__ float sigm_f(float x) {
    return 1.f / (1.f + expf(-x));
}
__device__ __forceinline__ float tanh_f(float x) {
    return tanhf(x);
}
__device__ __forceinline__ void fma4(float4& a, const float4 w, const float4 x) {
    a.x = fmaf(w.x, x.x, a.x);
    a.y = fmaf(w.y, x.y, a.y);
    a.z = fmaf(w.z, x.z, a.z);
    a.w = fmaf(w.w, x.w, a.w);
}

// ---------------------------------------------------------------------------
// Persistent LSTM, whole T=1024 loop in one cooperative kernel.
// 256 blocks x 1024 threads; volatile LDS pad >80KB forces 1 block/CU.
// g = bid>>5 (8 batch groups of 16 rows), m = bid&31 (32 unit groups of 16).
//
// Per-step phase schedule (exchange latency hidden under independent work):
//   A: x@W_ih partials (x(t) staged last step; NO h dependency)
//   B: wait for h(t): leader wave polls remote flags (sc loads, 32 waves/line
//      chip-wide), releases siblings via LDS s_go (no LLC poll storm)
//   C: stage h(t) via agent-scope 8B loads -> LDS; __syncthreads
//   D: h@W_hh partials (same accumulators, same summation order); part[];sync
//   E: emb-row prefetch for x(t+1) issued to registers (latency hides under
//      epilogue); epilogue tid<256: reduce, gates, c/h update, sc h-store
//   F: drain-sync; leader sets flag(t+1); write prefetched x(t+1) to LDS; sync
//
// Race-freedom: 2 h buffers + flag(t+1)-after-own-h(t)-reads (phase order
// C -> F) gives the standard double-buffer guarantee. c tile block-owned (LDS).
__global__ __launch_bounds__(1024, 4) void lstm_persistent(
    const int* __restrict__ tokens, const float* __restrict__ emb,
    const float* __restrict__ W_ih, const float* __restrict__ b_ih,
    const float* __restrict__ W_hh, const float* __restrict__ b_hh,
    const float* __restrict__ h0, const float* __restrict__ c0,
    float* __restrict__ ws) {
    const int tid = threadIdx.x, bid = blockIdx.x;
    const int g = bid >> 5, m = bid & 31;

    float* h_buf  = ws + HBUF_OFF;
    float* last_h = ws + LASTH_OFF;
    float* last_c = ws + LASTC_OFF;
    int*   flags  = (int*)(ws + FLAG_OFF) + g * 64;   // 32 slots in one line

    __shared__ __align__(16) float  xh[16 * 772];   // [b][k], row-padded 768->772
    __shared__ float4 part[4 * 256];                // [kq][ul*16+b]
    __shared__ int    s_L[16];                      // per-batch Lsteps
    __shared__ float  s_c[256];                     // c[ul*16+b], block-owned
    __shared__ int    s_go;                         // intra-block release flag
    __shared__ float  lds_pad[4096];                // 16KB pad -> LDS>80KB -> 1 block/CU

    // volatile touch: NOT removable by DCE (round-2 pad was eliminated)
    {
        volatile float* vp = lds_pad;
        for (int i = tid; i < 4096; i += 1024) vp[i] = 0.f;
    }
    if (tid == 0) s_go = 0;

    // ---- per-batch lengths (all 32 blocks of a group compute identical s_L/Tg)
    if (tid < 16) s_L[tid] = T;
    __syncthreads();
    {
        const int b = tid >> 6;
        const int* tb = tokens + (size_t)(g * 16 + b) * T;
        int fz = T;
        for (int p = (tid & 63); p < T; p += 64)
            if (tb[p] == 0) fz = min(fz, p);
        atomicMin(&s_L[b], fz);
    }
    __syncthreads();
    if (tid < 16) {
        const int f = s_L[tid];
        s_L[tid] = (f == 0 || f == T) ? T : f;
    }
    __syncthreads();
    int Tg = 0;
#pragma unroll
    for (int i = 0; i < 16; ++i) Tg = max(Tg, s_L[i]);

    // ---- init block-owned c tile (same thread reads it later)
    if (tid < 256) {
        const int uli = tid >> 4, bi = tid & 15;
        s_c[tid] = c0[(size_t)(g * 16 + bi) * H + (m * 16 + uli)];
    }

    // ---- stage x(0)
    {
        const int b = tid >> 6, kq4 = tid & 63;
        const int tok = tokens[(size_t)(g * 16 + b) * T + 0];
        ((float4*)&xh[b * 772])[kq4] =
            ((const float4*)emb)[(size_t)tok * 64 + kq4];
    }

    // ---- compute-role constants
    const int kq = tid >> 8, ul = (tid >> 4) & 15, cb = tid & 15;
    const int unit = m * 16 + ul;
    const float4* Wi = (const float4*)W_ih;
    const float4* Wh = (const float4*)W_hh;
    const float4* wr0 = Wi + (size_t)(unit) * 64;
    const float4* wr1 = Wi + (size_t)(H + unit) * 64;
    const float4* wr2 = Wi + (size_t)(2 * H + unit) * 64;
    const float4* wr3 = Wi + (size_t)(3 * H + unit) * 64;
    const float4* vr0 = Wh + (size_t)(unit) * 128;
    const float4* vr1 = Wh + (size_t)(H + unit) * 128;
    const float4* vr2 = Wh + (size_t)(2 * H + unit) * 128;
    const float4* vr3 = Wh + (size_t)(3 * H + unit) * 128;
    const int k4lo = kq * 48, k4hi = k4lo + 48;
    const int xlo = min(k4lo, 64), xhi = min(k4hi, 64);
    const int hlo = max(k4lo, 64) - 64, hhi = max(k4hi, 64) - 64;
    const float4* xb = (const float4*)&xh[cb * 772];

    // ---- epilogue constants
    const int ul2 = tid >> 4, b2 = tid & 15;
    const int unit2 = m * 16 + (ul2 & 15);
    const int bg = g * 16 + b2;
    const float bi_i = b_ih[unit2],         bh_i = b_hh[unit2];
    const float bi_f = b_ih[H + unit2],     bh_f = b_hh[H + unit2];
    const float bi_g = b_ih[2 * H + unit2], bh_g = b_hh[2 * H + unit2];
    const float bi_o = b_ih[3 * H + unit2], bh_o = b_hh[3 * H + unit2];

    __syncthreads();   // x(0), s_L, s_go visible before loop

    for (int t = 0; t < Tg; ++t) {
        // ---- Phase A: x-part partial dots (no h dependency; hides exchange)
        float4 s0 = {0, 0, 0, 0}, s1 = {0, 0, 0, 0};
        float4 s2 = {0, 0, 0, 0}, s3 = {0, 0, 0, 0};
#pragma unroll 4
        for (int k4 = xlo; k4 < xhi; ++k4) {
            const float4 x = xb[k4];
            fma4(s0, wr0[k4], x);
            fma4(s1, wr1[k4], x);
            fma4(s2, wr2[k4], x);
            fma4(s3, wr3[k4], x);
        }

        // ---- Phase B: wait for h(t) (leader wave polls LLC; LDS release)
        if (t > 0) {
            if (tid < 64) {
                const int* slot = &flags[tid & 31];
                while (true) {
                    const int v = __hip_atomic_load(slot, __ATOMIC_RELAXED,
                                                    __HIP_MEMORY_SCOPE_AGENT);
                    if (__all(v >= t)) break;
                    __builtin_amdgcn_s_sleep(1);
                }
                if (tid == 0)
                    __hip_atomic_store(&s_go, t, __ATOMIC_RELAXED,
                                       __HIP_MEMORY_SCOPE_WORKGROUP);
            } else {
                while (__hip_atomic_load(&s_go, __ATOMIC_RELAXED,
                                         __HIP_MEMORY_SCOPE_WORKGROUP) < t)
                    __builtin_amdgcn_s_sleep(1);
            }
        }

        // ---- Phase C: stage h(t) into xh[b][256+u]
        if (t == 0) {
            const int b = tid >> 6, l = tid & 63;
            const float4* h04 = (const float4*)(h0 + (size_t)(g * 16 + b) * H);
            float4* dst = (float4*)&xh[b * 772 + 256];
            dst[l]      = h04[l];
            dst[64 + l] = h04[64 + l];
        } else {
            // coherent 8B loads from LLC (bypass L1/L2; no cache maintenance)
            const unsigned long long* hs8 = (const unsigned long long*)
                (h_buf + (size_t)(t & 1) * (H * B));
            float2 hv[4];
#pragma unroll
            for (int j = 0; j < 4; ++j) {
                const int idx = j * 1024 + tid;        // [0,4096)
                const int u = idx >> 3, bp = idx & 7;
                unsigned long long v = __hip_atomic_load(
                    &hs8[(size_t)u * 64 + g * 8 + bp],
                    __ATOMIC_RELAXED, __HIP_MEMORY_SCOPE_AGENT);
                hv[j] = __builtin_bit_cast(float2, v);
            }
#pragma unroll
            for (int j = 0; j < 4; ++j) {
                const int idx = j * 1024 + tid;
                const int u = idx >> 3, bp = idx & 7;
                xh[(2 * bp) * 772 + 256 + u]     = hv[j].x;
                xh[(2 * bp + 1) * 772 + 256 + u] = hv[j].y;
            }
        }
        __syncthreads();

        // ---- Phase D: h-part partial dots (same accumulators, same order)
#pragma unroll 4
        for (int k4 = hlo; k4 < hhi; ++k4) {
            const float4 x = xb[64 + k4];
            fma4(s0, vr0[k4], x);
            fma4(s1, vr1[k4], x);
            fma4(s2, vr2[k4], x);
            fma4(s3, vr3[k4], x);
        }
        float4 p;
        p.x = s0.x + s0.y + s0.z + s0.w;
        p.y = s1.x + s1.y + s1.z + s1.w;
        p.z = s2.x + s2.y + s2.z + s2.w;
        p.w = s3.x + s3.y + s3.z + s3.w;
        part[kq * 256 + (ul * 16 + cb)] = p;
        __syncthreads();

        // ---- Phase E: emb prefetch for x(t+1) (latency hides under epilogue)
        float4 xreg;
        const bool do_stage = (t + 1 < Tg);
        if (do_stage) {
            const int b = tid >> 6, kq4 = tid & 63;
            const int tok = tokens[(size_t)(g * 16 + b) * T + (t + 1)];
            xreg = ((const float4*)emb)[(size_t)tok * 64 + kq4];
        }

        // ---- epilogue: finish gates + elementwise (tid<256)
        if (tid < 256) {
            const float4 q0 = part[tid],       q1 = part[256 + tid];
            const float4 q2 = part[512 + tid], q3 = part[768 + tid];
            const float ai = (q0.x + q1.x) + (q2.x + q3.x) + bi_i + bh_i;
            const float af = (q0.y + q1.y) + (q2.y + q3.y) + bi_f + bh_f;
            const float ag = (q0.z + q1.z) + (q2.z + q3.z) + bi_g + bh_g;
            const float ao = (q0.w + q1.w) + (q2.w + q3.w) + bi_o + bh_o;

            const float ig = sigm_f(ai);
            const float fg = sigm_f(af);
            const float gv = tanh_f(ag);
            const float og = sigm_f(ao);

            const float c_old = s_c[tid];
            const float c_new = fg * c_old + ig * gv;
            const float h_new = og * tanh_f(c_new);
            s_c[tid] = c_new;

            const int idx = unit2 * B + bg;
            __hip_atomic_store(&h_buf[(size_t)((t + 1) & 1) * (H * B) + idx],
                               h_new, __ATOMIC_RELAXED,
                               __HIP_MEMORY_SCOPE_AGENT);
            if (t == s_L[b2] - 1) {
                last_h[idx] = h_new;
                last_c[idx] = c_new;
            }
        }

        // ---- Phase F: handoff to step t+1
        if (do_stage) {
            __syncthreads();   // drains vmcnt: h-stores (and xreg load) done
            if (tid == 0)
                __hip_atomic_store(&flags[m], t + 1, __ATOMIC_RELAXED,
                                   __HIP_MEMORY_SCOPE_AGENT);
            {
                const int b = tid >> 6, kq4 = tid & 63;
                ((float4*)&xh[b * 772])[kq4] = xreg;
            }
            __syncthreads();   // x(t+1) staged before next Phase A
        }
    }
}

// ---------------------------------------------------------------------------
// final: y = [h;c] @ W_proj^T + b_proj ; out = y @ W_out^T + b_out
// grid 128 x 256 (unchanged)
__global__ __launch_bounds__(256) void final_kernel(
    const float* __restrict__ ws_ro, const float* __restrict__ W_proj,
    const float* __restrict__ b_proj, const float* __restrict__ W_out,
    const float* __restrict__ b_out, float* __restrict__ out) {
    const int bg = blockIdx.x, tid = threadIdx.x;
    const float* last_h = ws_ro + LASTH_OFF;
    const float* last_c = ws_ro + LASTC_OFF;

    __shared__ __align__(16) float s_hc[2 * H];
    __shared__ float s_y[H];
    for (int u = tid; u < H; u += 256) {
        s_hc[u]     = last_h[u * B + bg];
        s_hc[H + u] = last_c[u * B + bg];
    }
    __syncthreads();

    const float4* hc4 = (const float4*)s_hc;
    const float4* Wp4 = (const float4*)W_proj;
#pragma unroll
    for (int jj = 0; jj < 2; ++jj) {
        const int j = tid + jj * 256;
        const float4* wr = Wp4 + (size_t)j * 256;
        float4 acc = {0, 0, 0, 0};
#pragma unroll 4
        for (int kq = 0; kq < 256; ++kq) fma4(acc, wr[kq], hc4[kq]);
        s_y[j] = acc.x + acc.y + acc.z + acc.w + b_proj[j];
    }
    __syncthreads();

    if (tid < 64) {
        float p0 = 0.f, p1 = 0.f;
        for (int j = tid; j < H; j += 64) {
            const float y = s_y[j];
            p0 = fmaf(y, W_out[j], p0);
            p1 = fmaf(y, W_out[H + j], p1);
        }
#pragma unroll
        for (int off = 32; off; off >>= 1) {
            p0 += __shfl_down(p0, off);
            p1 += __shfl_down(p1, off);
        }
        if (tid == 0) {
            out[bg * 2 + 0] = p0 + b_out[0];
            out[bg * 2 + 1] = p1 + b_out[1];
        }
    }
}

// ---------------------------------------------------------------------------
extern "C" void kernel_launch(void* const* d_in, const int* in_sizes, int n_in,
                              void* d_out, int out_size, void* d_ws, size_t ws_size,
                              hipStream_t stream) {
    const int*   tokens = (const int*)d_in[0];
    const float* emb    = (const float*)d_in[1];
    const float* W_ih   = (const float*)d_in[2];
    const float* b_ih   = (const float*)d_in[3];
    const float* W_hh   = (const float*)d_in[4];
    const float* b_hh   = (const float*)d_in[5];
    const float* W_proj = (const float*)d_in[6];
    const float* b_proj = (const float*)d_in[7];
    const float* W_out  = (const float*)d_in[8];
    const float* b_out  = (const float*)d_in[9];
    const float* h0     = (const float*)d_in[10];
    const float* c0     = (const float*)d_in[11];
    float* out = (float*)d_out;
    float* ws  = (float*)d_ws;

    // zero the per-group flag slots (required every launch/replay)
    hipMemsetAsync((char*)d_ws + (size_t)FLAG_OFF * sizeof(float), 0,
                   8 * 64 * sizeof(int), stream);

    void* kargs[] = {(void*)&tokens, (void*)&emb, (void*)&W_ih, (void*)&b_ih,
                     (void*)&W_hh, (void*)&b_hh, (void*)&h0, (void*)&c0,
                     (void*)&ws};
    // cooperative launch: guarantees all 256 blocks co-resident (1/CU with the
    // volatile LDS pad), which the flag barrier requires.
    hipLaunchCooperativeKernel((const void*)lstm_persistent, dim3(256),
                               dim3(1024), kargs, 0, stream);

    hipLaunchKernelGGL(final_kernel, dim3(B), dim3(256), 0, stream,
                       ws, W_proj, b_proj, W_out, b_out, out);
}

// Round 4
// 8774.372 us; speedup vs baseline: 4.0519x; 3.6474x over previous
//
#include <hip/hip_runtime.h>
#include <math.h>

// Problem constants
#define B 128
#define T 1024
#define E 256
#define H 512

// ws layout (floats):
//   h_buf : 2 * [512][128]  (double-buffered, [unit][batch])
//   last_h: [512][128]
//   last_c: [512][128]
//   flags : 8 groups x 64 ints (one 128B slot-line per group; slots 0..31 used)
#define HBUF_OFF   0
#define LASTH_OFF  (2*65536)
#define LASTC_OFF  (3*65536)
#define FLAG_OFF   (4*65536)

// Accurate transcendentals (OCML expf/tanhf).
__device__ __forceinline__ float sigm_f(float x) {
    return 1.f / (1.f + expf(-x));
}
__device__ __forceinline__ float tanh_f(float x) {
    return tanhf(x);
}

// 64-lane reduce-scatter of 32 per-lane values: after this, every lane's v[0]
// holds the full 64-lane sum of value index vi=(lane>>1)&31. All indices are
// compile-time (full unroll) -> stays in registers (no scratch).
__device__ __forceinline__ void reduce32(float (&v)[32], int lane) {
#define RR(MASK, HALF)                                                 \
    {                                                                  \
        const bool hi = (lane & MASK) != 0;                            \
        _Pragma("unroll")                                              \
        for (int i = 0; i < HALF; ++i) {                               \
            const float mine   = hi ? v[i + HALF] : v[i];              \
            const float theirs = hi ? v[i] : v[i + HALF];              \
            v[i] = mine + __shfl_xor(theirs, MASK);                    \
        }                                                              \
    }
    RR(32, 16)
    RR(16, 8)
    RR(8, 4)
    RR(4, 2)
    RR(2, 1)
#undef RR
    v[0] = v[0] + __shfl_xor(v[0], 1);
}

// ---------------------------------------------------------------------------
// Persistent LSTM, whole T=1024 loop in one cooperative kernel.
// 256 blocks x 1024 threads; volatile LDS pad >80KB forces 1 block/CU.
// g = bid>>5 (8 batch groups of 16 rows), m = bid&31 (32 unit groups of 16).
//
// KEY CHANGE vs R3: wave-per-unit decomposition with REGISTER-PERSISTENT
// weights. Wave w owns unit m*16+w; lane l owns K f4-slots {l, 64+l, 128+l}
// => 12 float4 weights/lane (48 VGPR) loaded ONCE before the t-loop.
// Weight L2 traffic per step: 0 (was 800 MB/step chip-wide, the real
// bottleneck of every previous round). LDS x/h reads drop 4x (48 vs 192
// b128/lane/step). Gate partials reduced with a 6-round shfl_xor
// reduce-scatter (no part[] LDS round-trip).
//
// Per-step schedule: A: x-part dots batches 0..7 (no h dep, hides exchange)
//   B: wait h(t) flags (leader wave + LDS s_go release)
//   C: stage h(t) -> LDS; sync
//   D: h-part dots batches 0..7; reduce; sgate
//   E: full dots batches 8..15; reduce; sgate
//   F: x(t+1) prefetch to reg; sync; epilogue (tid<256) + h sc-stores;
//      drain-sync; flag(t+1); write x(t+1); sync
// Race-freedom: identical double-buffer + flag protocol as R3 (proven).
__global__ __launch_bounds__(1024, 4) void lstm_persistent(
    const int* __restrict__ tokens, const float* __restrict__ emb,
    const float* __restrict__ W_ih, const float* __restrict__ b_ih,
    const float* __restrict__ W_hh, const float* __restrict__ b_hh,
    const float* __restrict__ h0, const float* __restrict__ c0,
    float* __restrict__ ws) {
    const int tid = threadIdx.x, bid = blockIdx.x;
    const int g = bid >> 5, m = bid & 31;

    float* h_buf  = ws + HBUF_OFF;
    float* last_h = ws + LASTH_OFF;
    float* last_c = ws + LASTC_OFF;
    int*   flags  = (int*)(ws + FLAG_OFF) + g * 64;   // 32 slots in one line

    __shared__ __align__(16) float xh[16 * 772];   // [b][k], row stride 772
    __shared__ float sgate[4][16][17];             // [gate][unit-local][batch]
    __shared__ int   s_L[16];                      // per-batch Lsteps
    __shared__ float s_c[256];                     // c[ul*16+b], block-owned
    __shared__ int   s_go;                         // intra-block release flag
    __shared__ float lds_pad[8192];                // 32KB pad -> LDS>80KB -> 1 block/CU

    // volatile touch: not removable by DCE
    {
        volatile float* vp = lds_pad;
        for (int i = tid; i < 8192; i += 1024) vp[i] = 0.f;
    }
    if (tid == 0) s_go = 0;

    // ---- per-batch lengths (all 32 blocks of a group compute identical s_L/Tg)
    if (tid < 16) s_L[tid] = T;
    __syncthreads();
    {
        const int b = tid >> 6;
        const int* tb = tokens + (size_t)(g * 16 + b) * T;
        int fz = T;
        for (int p = (tid & 63); p < T; p += 64)
            if (tb[p] == 0) fz = min(fz, p);
        atomicMin(&s_L[b], fz);
    }
    __syncthreads();
    if (tid < 16) {
        const int f = s_L[tid];
        s_L[tid] = (f == 0 || f == T) ? T : f;
    }
    __syncthreads();
    int Tg = 0;
#pragma unroll
    for (int i = 0; i < 16; ++i) Tg = max(Tg, s_L[i]);

    // ---- init block-owned c tile
    if (tid < 256) {
        const int uli = tid >> 4, bi = tid & 15;
        s_c[tid] = c0[(size_t)(g * 16 + bi) * H + (m * 16 + uli)];
    }

    // ---- stage x(0)
    {
        const int b = tid >> 6, kq4 = tid & 63;
        const int tok = tokens[(size_t)(g * 16 + b) * T + 0];
        ((float4*)&xh[b * 772])[kq4] =
            ((const float4*)emb)[(size_t)tok * 64 + kq4];
    }

    // ---- wave/lane roles + REGISTER-PERSISTENT weights (held all T steps)
    const int lane = tid & 63;
    const int w    = tid >> 6;            // wave index = local unit
    const int unit = m * 16 + w;
    const float4* Wi4 = (const float4*)W_ih;
    const float4* Wh4 = (const float4*)W_hh;
    float4 wx[4], wh0[4], wh1[4];         // 12 f4 = 48 VGPR
#pragma unroll
    for (int G = 0; G < 4; ++G) {
        wx[G]  = Wi4[((size_t)G * H + unit) * 64 + lane];
        wh0[G] = Wh4[((size_t)G * H + unit) * 128 + lane];
        wh1[G] = Wh4[((size_t)G * H + unit) * 128 + 64 + lane];
    }

    // ---- epilogue constants (used for tid<256; loads in-bounds for all)
    const int ul2 = tid >> 4, b2 = tid & 15;
    const int unit2 = m * 16 + (ul2 & 15);
    const int bg = g * 16 + b2;
    const float bi_i = b_ih[unit2],         bh_i = b_hh[unit2];
    const float bi_f = b_ih[H + unit2],     bh_f = b_hh[H + unit2];
    const float bi_g = b_ih[2 * H + unit2], bh_g = b_hh[2 * H + unit2];
    const float bi_o = b_ih[3 * H + unit2], bh_o = b_hh[3 * H + unit2];

    __syncthreads();   // x(0), s_L, s_c, s_go visible

    float v[32];

    for (int t = 0; t < Tg; ++t) {
        // ---- Phase A: x-part, batches 0..7 (no h dependency; hides exchange)
#pragma unroll
        for (int bb = 0; bb < 8; ++bb) {
            const float4 x = ((const float4*)&xh[bb * 772])[lane];
#pragma unroll
            for (int G = 0; G < 4; ++G) {
                float p = wx[G].x * x.x;
                p = fmaf(wx[G].y, x.y, p);
                p = fmaf(wx[G].z, x.z, p);
                p = fmaf(wx[G].w, x.w, p);
                v[G * 8 + bb] = p;
            }
        }

        // ---- Phase B: wait for h(t) (leader wave polls LLC; LDS release)
        if (t > 0) {
            if (tid < 64) {
                const int* slot = &flags[tid & 31];
                while (true) {
                    const int fv = __hip_atomic_load(slot, __ATOMIC_RELAXED,
                                                     __HIP_MEMORY_SCOPE_AGENT);
                    if (__all(fv >= t)) break;
                    __builtin_amdgcn_s_sleep(1);
                }
                if (tid == 0)
                    __hip_atomic_store(&s_go, t, __ATOMIC_RELAXED,
                                       __HIP_MEMORY_SCOPE_WORKGROUP);
            } else {
                while (__hip_atomic_load(&s_go, __ATOMIC_RELAXED,
                                         __HIP_MEMORY_SCOPE_WORKGROUP) < t)
                    __builtin_amdgcn_s_sleep(1);
            }
        }

        // ---- Phase C: stage h(t) into xh[b][256+u]
        if (t == 0) {
            const int b = tid >> 6, l = tid & 63;
            const float4* h04 = (const float4*)(h0 + (size_t)(g * 16 + b) * H);
            float4* dst = (float4*)&xh[b * 772 + 256];
            dst[l]      = h04[l];
            dst[64 + l] = h04[64 + l];
        } else {
            // coherent 8B loads from LLC (bypass L1/L2; no cache maintenance)
            const unsigned long long* hs8 = (const unsigned long long*)
                (h_buf + (size_t)(t & 1) * (H * B));
            float2 hv[4];
#pragma unroll
            for (int j = 0; j < 4; ++j) {
                const int idx = j * 1024 + tid;        // [0,4096)
                const int u = idx >> 3, bp = idx & 7;
                unsigned long long val = __hip_atomic_load(
                    &hs8[(size_t)u * 64 + g * 8 + bp],
                    __ATOMIC_RELAXED, __HIP_MEMORY_SCOPE_AGENT);
                hv[j] = __builtin_bit_cast(float2, val);
            }
#pragma unroll
            for (int j = 0; j < 4; ++j) {
                const int idx = j * 1024 + tid;
                const int u = idx >> 3, bp = idx & 7;
                xh[(2 * bp) * 772 + 256 + u]     = hv[j].x;
                xh[(2 * bp + 1) * 772 + 256 + u] = hv[j].y;
            }
        }
        __syncthreads();

        // ---- Phase D: h-part batches 0..7; reduce; sgate
#pragma unroll
        for (int bb = 0; bb < 8; ++bb) {
            const float4 ha = ((const float4*)&xh[bb * 772])[64 + lane];
            const float4 hb = ((const float4*)&xh[bb * 772])[128 + lane];
#pragma unroll
            for (int G = 0; G < 4; ++G) {
                float p = v[G * 8 + bb];
                p = fmaf(wh0[G].x, ha.x, p);
                p = fmaf(wh0[G].y, ha.y, p);
                p = fmaf(wh0[G].z, ha.z, p);
                p = fmaf(wh0[G].w, ha.w, p);
                p = fmaf(wh1[G].x, hb.x, p);
                p = fmaf(wh1[G].y, hb.y, p);
                p = fmaf(wh1[G].z, hb.z, p);
                p = fmaf(wh1[G].w, hb.w, p);
                v[G * 8 + bb] = p;
            }
        }
        reduce32(v, lane);
        if ((lane & 1) == 0) {
            const int vi = (lane >> 1) & 31;
            sgate[vi >> 3][w][vi & 7] = v[0];
        }

        // ---- Phase E: full dots batches 8..15; reduce; sgate
#pragma unroll
        for (int bb = 0; bb < 8; ++bb) {
            const float4 x  = ((const float4*)&xh[(8 + bb) * 772])[lane];
            const float4 ha = ((const float4*)&xh[(8 + bb) * 772])[64 + lane];
            const float4 hb = ((const float4*)&xh[(8 + bb) * 772])[128 + lane];
#pragma unroll
            for (int G = 0; G < 4; ++G) {
                float p = wx[G].x * x.x;
                p = fmaf(wx[G].y, x.y, p);
                p = fmaf(wx[G].z, x.z, p);
                p = fmaf(wx[G].w, x.w, p);
                p = fmaf(wh0[G].x, ha.x, p);
                p = fmaf(wh0[G].y, ha.y, p);
                p = fmaf(wh0[G].z, ha.z, p);
                p = fmaf(wh0[G].w, ha.w, p);
                p = fmaf(wh1[G].x, hb.x, p);
                p = fmaf(wh1[G].y, hb.y, p);
                p = fmaf(wh1[G].z, hb.z, p);
                p = fmaf(wh1[G].w, hb.w, p);
                v[G * 8 + bb] = p;
            }
        }
        reduce32(v, lane);
        if ((lane & 1) == 0) {
            const int vi = (lane >> 1) & 31;
            sgate[vi >> 3][w][8 + (vi & 7)] = v[0];
        }

        // ---- Phase F: x(t+1) prefetch (latency hides under epilogue)
        float4 xreg;
        const bool do_stage = (t + 1 < Tg);
        if (do_stage) {
            const int b = tid >> 6, kq4 = tid & 63;
            const int tok = tokens[(size_t)(g * 16 + b) * T + (t + 1)];
            xreg = ((const float4*)emb)[(size_t)tok * 64 + kq4];
        }
        __syncthreads();   // sgate complete before epilogue reads

        // ---- epilogue: gates + elementwise (tid<256)
        if (tid < 256) {
            const float ai = sgate[0][ul2][b2] + bi_i + bh_i;
            const float af = sgate[1][ul2][b2] + bi_f + bh_f;
            const float ag = sgate[2][ul2][b2] + bi_g + bh_g;
            const float ao = sgate[3][ul2][b2] + bi_o + bh_o;

            const float ig = sigm_f(ai);
            const float fg = sigm_f(af);
            const float gv = tanh_f(ag);
            const float og = sigm_f(ao);

            const float c_old = s_c[tid];
            const float c_new = fg * c_old + ig * gv;
            const float h_new = og * tanh_f(c_new);
            s_c[tid] = c_new;

            const int idx = unit2 * B + bg;
            __hip_atomic_store(&h_buf[(size_t)((t + 1) & 1) * (H * B) + idx],
                               h_new, __ATOMIC_RELAXED,
                               __HIP_MEMORY_SCOPE_AGENT);
            if (t == s_L[b2] - 1) {
                last_h[idx] = h_new;
                last_c[idx] = c_new;
            }
        }

        // ---- handoff to step t+1
        if (do_stage) {
            __syncthreads();   // drains vmcnt: h-stores at LLC
            if (tid == 0)
                __hip_atomic_store(&flags[m], t + 1, __ATOMIC_RELAXED,
                                   __HIP_MEMORY_SCOPE_AGENT);
            {
                const int b = tid >> 6, kq4 = tid & 63;
                ((float4*)&xh[b * 772])[kq4] = xreg;
            }
            __syncthreads();   // x(t+1) staged before next Phase A
        }
    }
}

// ---------------------------------------------------------------------------
// final: y = [h;c] @ W_proj^T + b_proj ; out = y @ W_out^T + b_out
// grid 128 x 256 (unchanged)
__global__ __launch_bounds__(256) void final_kernel(
    const float* __restrict__ ws_ro, const float* __restrict__ W_proj,
    const float* __restrict__ b_proj, const float* __restrict__ W_out,
    const float* __restrict__ b_out, float* __restrict__ out) {
    const int bg = blockIdx.x, tid = threadIdx.x;
    const float* last_h = ws_ro + LASTH_OFF;
    const float* last_c = ws_ro + LASTC_OFF;

    __shared__ __align__(16) float s_hc[2 * H];
    __shared__ float s_y[H];
    for (int u = tid; u < H; u += 256) {
        s_hc[u]     = last_h[u * B + bg];
        s_hc[H + u] = last_c[u * B + bg];
    }
    __syncthreads();

    const float4* hc4 = (const float4*)s_hc;
    const float4* Wp4 = (const float4*)W_proj;
#pragma unroll
    for (int jj = 0; jj < 2; ++jj) {
        const int j = tid + jj * 256;
        const float4* wr = Wp4 + (size_t)j * 256;
        float4 acc = {0, 0, 0, 0};
#pragma unroll 4
        for (int kq = 0; kq < 256; ++kq) {
            acc.x = fmaf(wr[kq].x, hc4[kq].x, acc.x);
            acc.y = fmaf(wr[kq].y, hc4[kq].y, acc.y);
            acc.z = fmaf(wr[kq].z, hc4[kq].z, acc.z);
            acc.w = fmaf(wr[kq].w, hc4[kq].w, acc.w);
        }
        s_y[j] = acc.x + acc.y + acc.z + acc.w + b_proj[j];
    }
    __syncthreads();

    if (tid < 64) {
        float p0 = 0.f, p1 = 0.f;
        for (int j = tid; j < H; j += 64) {
            const float y = s_y[j];
            p0 = fmaf(y, W_out[j], p0);
            p1 = fmaf(y, W_out[H + j], p1);
        }
#pragma unroll
        for (int off = 32; off; off >>= 1) {
            p0 += __shfl_down(p0, off);
            p1 += __shfl_down(p1, off);
        }
        if (tid == 0) {
            out[bg * 2 + 0] = p0 + b_out[0];
            out[bg * 2 + 1] = p1 + b_out[1];
        }
    }
}

// ---------------------------------------------------------------------------
extern "C" void kernel_launch(void* const* d_in, const int* in_sizes, int n_in,
                              void* d_out, int out_size, void* d_ws, size_t ws_size,
                              hipStream_t stream) {
    const int*   tokens = (const int*)d_in[0];
    const float* emb    = (const float*)d_in[1];
    const float* W_ih   = (const float*)d_in[2];
    const float* b_ih   = (const float*)d_in[3];
    const float* W_hh   = (const float*)d_in[4];
    const float* b_hh   = (const float*)d_in[5];
    const float* W_proj = (const float*)d_in[6];
    const float* b_proj = (const float*)d_in[7];
    const float* W_out  = (const float*)d_in[8];
    const float* b_out  = (const float*)d_in[9];
    const float* h0     = (const float*)d_in[10];
    const float* c0     = (const float*)d_in[11];
    float* out = (float*)d_out;
    float* ws  = (float*)d_ws;

    // zero the per-group flag slots (required every launch/replay)
    hipMemsetAsync((char*)d_ws + (size_t)FLAG_OFF * sizeof(float), 0,
                   8 * 64 * sizeof(int), stream);

    void* kargs[] = {(void*)&tokens, (void*)&emb, (void*)&W_ih, (void*)&b_ih,
                     (void*)&W_hh, (void*)&b_hh, (void*)&h0, (void*)&c0,
                     (void*)&ws};
    // cooperative launch: guarantees all 256 blocks co-resident (1/CU with the
    // volatile LDS pad), which the flag barrier requires.
    hipLaunchCooperativeKernel((const void*)lstm_persistent, dim3(256),
                               dim3(1024), kargs, 0, stream);

    hipLaunchKernelGGL(final_kernel, dim3(B), dim3(256), 0, stream,
                       ws, W_proj, b_proj, W_out, b_out, out);
}